// Round 5
// baseline (55.251 us; speedup 1.0000x reference)
//
#include <hip/hip_runtime.h>

#define EPSILON 1e-7

constexpr int BLOCKS  = 8192;
constexpr int THREADS = 256;

// Stage 1: per-block partial sums of {s0, s1, n1}
//   c0 = p < 0.5 ? p : 1-p
//   s0 = sum of c0 where t==0, s1 = sum of c0 where t==1, n1 = count of t==1
// Specialized: when n4 == 4*stride (N=2^25 with 8192x256), each thread does
// exactly 4 chunks, fully unrolled, all 8 vector loads issued up front.
__global__ __launch_bounds__(THREADS) void f1_partial_kernel(
    const float* __restrict__ pred,
    const int*   __restrict__ truth,
    float*       __restrict__ partial,   // [3][BLOCKS] SoA
    int n4)
{
    float s0 = 0.0f, s1 = 0.0f;
    int   c1 = 0;

    const float4* p4 = reinterpret_cast<const float4*>(pred);
    const int4*   t4 = reinterpret_cast<const int4*>(truth);

    int idx    = blockIdx.x * blockDim.x + threadIdx.x;
    int stride = gridDim.x * blockDim.x;

    auto accum = [&](float4 p, int4 t) {
        float c;
        c = (p.x < 0.5f) ? p.x : 1.0f - p.x; if (t.x) s1 += c; else s0 += c; c1 += t.x;
        c = (p.y < 0.5f) ? p.y : 1.0f - p.y; if (t.y) s1 += c; else s0 += c; c1 += t.y;
        c = (p.z < 0.5f) ? p.z : 1.0f - p.z; if (t.z) s1 += c; else s0 += c; c1 += t.z;
        c = (p.w < 0.5f) ? p.w : 1.0f - p.w; if (t.w) s1 += c; else s0 += c; c1 += t.w;
    };

    if (n4 == 4 * stride) {
        // exact-fit fast path: 4 chunks/thread, no loop, max MLP
        float4 pa = p4[idx];
        int4   ta = t4[idx];
        float4 pb = p4[idx + stride];
        int4   tb = t4[idx + stride];
        float4 pc = p4[idx + 2 * stride];
        int4   tc = t4[idx + 2 * stride];
        float4 pd = p4[idx + 3 * stride];
        int4   td = t4[idx + 3 * stride];
        accum(pa, ta); accum(pb, tb); accum(pc, tc); accum(pd, td);
    } else {
        for (int i = idx; i < n4; i += stride) accum(p4[i], t4[i]);
    }

    // wave (64-lane) shuffle reduction
    #pragma unroll
    for (int off = 32; off > 0; off >>= 1) {
        s0 += __shfl_down(s0, off);
        s1 += __shfl_down(s1, off);
        c1 += __shfl_down(c1, off);
    }

    __shared__ float ls0[THREADS / 64];
    __shared__ float ls1[THREADS / 64];
    __shared__ int   lc1[THREADS / 64];

    int lane = threadIdx.x & 63;
    int wave = threadIdx.x >> 6;
    if (lane == 0) { ls0[wave] = s0; ls1[wave] = s1; lc1[wave] = c1; }
    __syncthreads();

    if (threadIdx.x == 0) {
        float t0 = 0.0f, t1 = 0.0f; int tc = 0;
        #pragma unroll
        for (int w = 0; w < THREADS / 64; ++w) { t0 += ls0[w]; t1 += ls1[w]; tc += lc1[w]; }
        partial[0 * BLOCKS + blockIdx.x] = t0;          // SoA: coalesced stage-2 reads
        partial[1 * BLOCKS + blockIdx.x] = t1;
        partial[2 * BLOCKS + blockIdx.x] = (float)tc;   // per-block count exact in f32
    }
}

// Stage 2: reduce per-block partials (SoA), compute F1 loss scalar
__global__ __launch_bounds__(THREADS) void f1_final_kernel(
    const float* __restrict__ partial,
    float*       __restrict__ out,
    int nblocks, double n_total)
{
    double s0 = 0.0, s1 = 0.0, c1 = 0.0;
    for (int i = threadIdx.x; i < nblocks; i += blockDim.x) {
        s0 += (double)partial[0 * nblocks + i];
        s1 += (double)partial[1 * nblocks + i];
        c1 += (double)partial[2 * nblocks + i];
    }

    #pragma unroll
    for (int off = 32; off > 0; off >>= 1) {
        s0 += __shfl_down(s0, off);
        s1 += __shfl_down(s1, off);
        c1 += __shfl_down(c1, off);
    }

    __shared__ double ds0[THREADS / 64];
    __shared__ double ds1[THREADS / 64];
    __shared__ double dc1[THREADS / 64];

    int lane = threadIdx.x & 63;
    int wave = threadIdx.x >> 6;
    if (lane == 0) { ds0[wave] = s0; ds1[wave] = s1; dc1[wave] = c1; }
    __syncthreads();

    if (threadIdx.x == 0) {
        double S0 = 0.0, S1 = 0.0, C1 = 0.0;
        #pragma unroll
        for (int w = 0; w < THREADS / 64; ++w) { S0 += ds0[w]; S1 += ds1[w]; C1 += dc1[w]; }

        double n1 = C1, n0 = n_total - n1;
        // class 0: tp=S0, fp=S1, fn=n0-S0
        // class 1: tp=n1-S1, fp=n0-S0, fn=S1
        double tp0 = S0,      fp0 = S1,      fn0 = n0 - S0;
        double tp1 = n1 - S1, fp1 = n0 - S0, fn1 = S1;

        double p0 = tp0 / (tp0 + fp0 + EPSILON);
        double r0 = tp0 / (tp0 + fn0 + EPSILON);
        double f0 = 2.0 * p0 * r0 / (p0 + r0 + EPSILON);
        f0 = fmin(fmax(f0, (double)EPSILON), 1.0 - (double)EPSILON);

        double p1 = tp1 / (tp1 + fp1 + EPSILON);
        double r1 = tp1 / (tp1 + fn1 + EPSILON);
        double f1 = 2.0 * p1 * r1 / (p1 + r1 + EPSILON);
        f1 = fmin(fmax(f1, (double)EPSILON), 1.0 - (double)EPSILON);

        out[0] = (float)(1.0 - 0.5 * (f0 + f1));
    }
}

extern "C" void kernel_launch(void* const* d_in, const int* in_sizes, int n_in,
                              void* d_out, int out_size, void* d_ws, size_t ws_size,
                              hipStream_t stream) {
    const float* pred    = (const float*)d_in[0];
    const int*   truth   = (const int*)d_in[1];
    float*       out     = (float*)d_out;
    float*       partial = (float*)d_ws;   // 3*BLOCKS floats = 96 KiB

    int n  = in_sizes[0];
    int n4 = n / 4;                        // N = 2^25, divisible by 4

    f1_partial_kernel<<<BLOCKS, THREADS, 0, stream>>>(pred, truth, partial, n4);
    f1_final_kernel<<<1, THREADS, 0, stream>>>(partial, out, BLOCKS, (double)n);
}

// Round 6
// 48.876 us; speedup vs baseline: 1.1305x; 1.1305x over previous
//
#include <hip/hip_runtime.h>

#define EPSILON 1e-7

constexpr int BLOCKS  = 2048;
constexpr int THREADS = 256;

// Stage 1: per-block partial sums of {s0, s1, n1}
//   c0 = p < 0.5 ? p : 1-p
//   s0 = sum of c0 where t==0, s1 = sum of c0 where t==1, n1 = count of t==1
// Grid-stride with manual x2 unroll: two independent 32B load pairs in flight.
__global__ __launch_bounds__(THREADS) void f1_partial_kernel(
    const float* __restrict__ pred,
    const int*   __restrict__ truth,
    float*       __restrict__ partial,   // [BLOCKS][3]
    int n4)                              // number of 4-element chunks
{
    float s0 = 0.0f, s1 = 0.0f;
    int   c1 = 0;

    const float4* p4 = reinterpret_cast<const float4*>(pred);
    const int4*   t4 = reinterpret_cast<const int4*>(truth);

    int idx    = blockIdx.x * blockDim.x + threadIdx.x;
    int stride = gridDim.x * blockDim.x;

    int i = idx;
    for (; i + stride < n4; i += 2 * stride) {
        // issue all 4 vector loads before consuming any
        float4 pa = p4[i];
        int4   ta = t4[i];
        float4 pb = p4[i + stride];
        int4   tb = t4[i + stride];
        float c;
        c = (pa.x < 0.5f) ? pa.x : 1.0f - pa.x; if (ta.x) s1 += c; else s0 += c; c1 += ta.x;
        c = (pa.y < 0.5f) ? pa.y : 1.0f - pa.y; if (ta.y) s1 += c; else s0 += c; c1 += ta.y;
        c = (pa.z < 0.5f) ? pa.z : 1.0f - pa.z; if (ta.z) s1 += c; else s0 += c; c1 += ta.z;
        c = (pa.w < 0.5f) ? pa.w : 1.0f - pa.w; if (ta.w) s1 += c; else s0 += c; c1 += ta.w;
        c = (pb.x < 0.5f) ? pb.x : 1.0f - pb.x; if (tb.x) s1 += c; else s0 += c; c1 += tb.x;
        c = (pb.y < 0.5f) ? pb.y : 1.0f - pb.y; if (tb.y) s1 += c; else s0 += c; c1 += tb.y;
        c = (pb.z < 0.5f) ? pb.z : 1.0f - pb.z; if (tb.z) s1 += c; else s0 += c; c1 += tb.z;
        c = (pb.w < 0.5f) ? pb.w : 1.0f - pb.w; if (tb.w) s1 += c; else s0 += c; c1 += tb.w;
    }
    for (; i < n4; i += stride) {
        float4 p = p4[i];
        int4   t = t4[i];
        float c;
        c = (p.x < 0.5f) ? p.x : 1.0f - p.x; if (t.x) s1 += c; else s0 += c; c1 += t.x;
        c = (p.y < 0.5f) ? p.y : 1.0f - p.y; if (t.y) s1 += c; else s0 += c; c1 += t.y;
        c = (p.z < 0.5f) ? p.z : 1.0f - p.z; if (t.z) s1 += c; else s0 += c; c1 += t.z;
        c = (p.w < 0.5f) ? p.w : 1.0f - p.w; if (t.w) s1 += c; else s0 += c; c1 += t.w;
    }

    // wave (64-lane) shuffle reduction
    #pragma unroll
    for (int off = 32; off > 0; off >>= 1) {
        s0 += __shfl_down(s0, off);
        s1 += __shfl_down(s1, off);
        c1 += __shfl_down(c1, off);
    }

    __shared__ float ls0[THREADS / 64];
    __shared__ float ls1[THREADS / 64];
    __shared__ int   lc1[THREADS / 64];

    int lane = threadIdx.x & 63;
    int wave = threadIdx.x >> 6;
    if (lane == 0) { ls0[wave] = s0; ls1[wave] = s1; lc1[wave] = c1; }
    __syncthreads();

    if (threadIdx.x == 0) {
        float t0 = 0.0f, t1 = 0.0f; int tc = 0;
        #pragma unroll
        for (int w = 0; w < THREADS / 64; ++w) { t0 += ls0[w]; t1 += ls1[w]; tc += lc1[w]; }
        partial[3 * blockIdx.x + 0] = t0;
        partial[3 * blockIdx.x + 1] = t1;
        partial[3 * blockIdx.x + 2] = (float)tc;   // per-block count exact in f32
    }
}

// Stage 2: reduce per-block partials, compute F1 loss scalar
__global__ __launch_bounds__(THREADS) void f1_final_kernel(
    const float* __restrict__ partial,
    float*       __restrict__ out,
    int nblocks, double n_total)
{
    double s0 = 0.0, s1 = 0.0, c1 = 0.0;
    for (int i = threadIdx.x; i < nblocks; i += blockDim.x) {
        s0 += (double)partial[3 * i + 0];
        s1 += (double)partial[3 * i + 1];
        c1 += (double)partial[3 * i + 2];
    }

    #pragma unroll
    for (int off = 32; off > 0; off >>= 1) {
        s0 += __shfl_down(s0, off);
        s1 += __shfl_down(s1, off);
        c1 += __shfl_down(c1, off);
    }

    __shared__ double ds0[THREADS / 64];
    __shared__ double ds1[THREADS / 64];
    __shared__ double dc1[THREADS / 64];

    int lane = threadIdx.x & 63;
    int wave = threadIdx.x >> 6;
    if (lane == 0) { ds0[wave] = s0; ds1[wave] = s1; dc1[wave] = c1; }
    __syncthreads();

    if (threadIdx.x == 0) {
        double S0 = 0.0, S1 = 0.0, C1 = 0.0;
        #pragma unroll
        for (int w = 0; w < THREADS / 64; ++w) { S0 += ds0[w]; S1 += ds1[w]; C1 += dc1[w]; }

        double n1 = C1, n0 = n_total - n1;
        // class 0: tp=S0, fp=S1, fn=n0-S0
        // class 1: tp=n1-S1, fp=n0-S0, fn=S1
        double tp0 = S0,      fp0 = S1,      fn0 = n0 - S0;
        double tp1 = n1 - S1, fp1 = n0 - S0, fn1 = S1;

        double p0 = tp0 / (tp0 + fp0 + EPSILON);
        double r0 = tp0 / (tp0 + fn0 + EPSILON);
        double f0 = 2.0 * p0 * r0 / (p0 + r0 + EPSILON);
        f0 = fmin(fmax(f0, (double)EPSILON), 1.0 - (double)EPSILON);

        double p1 = tp1 / (tp1 + fp1 + EPSILON);
        double r1 = tp1 / (tp1 + fn1 + EPSILON);
        double f1 = 2.0 * p1 * r1 / (p1 + r1 + EPSILON);
        f1 = fmin(fmax(f1, (double)EPSILON), 1.0 - (double)EPSILON);

        out[0] = (float)(1.0 - 0.5 * (f0 + f1));
    }
}

extern "C" void kernel_launch(void* const* d_in, const int* in_sizes, int n_in,
                              void* d_out, int out_size, void* d_ws, size_t ws_size,
                              hipStream_t stream) {
    const float* pred    = (const float*)d_in[0];
    const int*   truth   = (const int*)d_in[1];
    float*       out     = (float*)d_out;
    float*       partial = (float*)d_ws;   // BLOCKS*3 floats = 24 KiB

    int n  = in_sizes[0];
    int n4 = n / 4;                        // N = 2^25, divisible by 4

    f1_partial_kernel<<<BLOCKS, THREADS, 0, stream>>>(pred, truth, partial, n4);
    f1_final_kernel<<<1, THREADS, 0, stream>>>(partial, out, BLOCKS, (double)n);
}